// Round 13
// baseline (265.395 us; speedup 1.0000x reference)
//
#include <hip/hip_runtime.h>
#include <hip/hip_bf16.h>

// Problem constants (StateSpaceLayer): B=2, L=2048, D_MODEL=512, D_STATE=64,
// D_CONV=4, DT_RANK=32. All inputs/outputs fp32.
#define BSZ 2
#define SEQL 2048
#define DM 512
#define DST 64
#define DCONV 4
#define DTR 32
#define NROWS (BSZ * SEQL)   // 4096 flattened (b, t) rows

// Chunked scan decomposition
#define NC 32   // chunks per sequence
#define CL 64   // chunk length (NC*CL == SEQL)

// Combined projection output layout: xpd[row][640]
//   cols [0,64) = Bp, cols [64,128) = Cp, cols [128,640) = softplus(dt)
#define XPD_LD 640

typedef unsigned short u16;
typedef short bf16x8 __attribute__((ext_vector_type(8)));
typedef float f32x4 __attribute__((ext_vector_type(4)));

// Raw v_exp_f32 (2^x) / v_log_f32 (log2 x) without OCML fixup chains.
#if __has_builtin(__builtin_amdgcn_exp2f)
#define EXP2(x) __builtin_amdgcn_exp2f(x)
#else
#define EXP2(x) exp2f(x)
#endif
#if __has_builtin(__builtin_amdgcn_logf)
#define LOG2(x) __builtin_amdgcn_logf(x)
#else
#define LOG2(x) log2f(x)
#endif

// fp32 -> bf16 RNE split helpers (bit ops)
__device__ __forceinline__ u16 f2bf(float f) {
  unsigned u = __float_as_uint(f);
  return (u16)((u + 0x7FFFu + ((u >> 16) & 1u)) >> 16);
}
__device__ __forceinline__ float bf2f(u16 h) {
  return __uint_as_float(((unsigned)h) << 16);
}

// async global->LDS, 16B per lane (dest = wave-uniform base + lane*16)
__device__ __forceinline__ void gload_lds16(const u16* g, u16* l) {
  __builtin_amdgcn_global_load_lds(
      (const __attribute__((address_space(1))) void*)(const void*)g,
      (__attribute__((address_space(3))) void*)(void*)l, 16, 0, 0);
}

// ---------------------------------------------------------------------------
// Split conversion kernels.
// ---------------------------------------------------------------------------
__global__ __launch_bounds__(256) void split_x_kernel(
    const float* __restrict__ x, u16* __restrict__ hi, u16* __restrict__ lo) {
  int idx = (blockIdx.x * 256 + threadIdx.x) * 4;  // over NROWS*DM
  float4 v = *(const float4*)(x + idx);
  ushort4 h, l;
  h.x = f2bf(v.x); l.x = f2bf(v.x - bf2f(h.x));
  h.y = f2bf(v.y); l.y = f2bf(v.y - bf2f(h.y));
  h.z = f2bf(v.z); l.z = f2bf(v.z - bf2f(h.z));
  h.w = f2bf(v.w); l.w = f2bf(v.w - bf2f(h.w));
  *(ushort4*)(hi + idx) = h;
  *(ushort4*)(lo + idx) = l;
}

__global__ __launch_bounds__(256) void split_w_kernel(
    const float* __restrict__ W, u16* __restrict__ Wt_hi,
    u16* __restrict__ Wt_lo) {
  __shared__ u16 shi[32][33], slo[32][33];
  const int n0 = blockIdx.x * 32;  // 32 blocks over N=1024
  const int k0 = blockIdx.y * 32;  // 16 blocks over K=512
  const int i = threadIdx.x >> 5;  // 0..7
  const int j = threadIdx.x & 31;
#pragma unroll
  for (int r = 0; r < 4; ++r) {
    int k = i + r * 8;
    float v = W[(size_t)(k0 + k) * 1024 + n0 + j];
    u16 h = f2bf(v);
    shi[k][j] = h;
    slo[k][j] = f2bf(v - bf2f(h));
  }
  __syncthreads();
#pragma unroll
  for (int r = 0; r < 4; ++r) {
    int n = i + r * 8;  // row of Wt within tile
    Wt_hi[(size_t)(n0 + n) * 512 + k0 + j] = shi[j][n];
    Wt_lo[(size_t)(n0 + n) * 512 + k0 + j] = slo[j][n];
  }
}

// ---------------------------------------------------------------------------
// Combined projection weight: Wt_c [640][512] bf16 split, transposed.
//   row r<128:  Wt_c[r][k] = x_proj_w[k][32+r]                 (Bp/Cp cols)
//   row 128+d:  Wt_c[128+d][k] = sum_j x_proj_w[k][j]*dt_proj_w[j][d], j<32
// ---------------------------------------------------------------------------
__global__ __launch_bounds__(256) void w_combine_kernel(
    const float* __restrict__ xw, const float* __restrict__ dw,
    u16* __restrict__ Wt_hi, u16* __restrict__ Wt_lo) {
  int idx = blockIdx.x * 256 + threadIdx.x;  // over 640*512
  int r = idx >> 9;
  int k = idx & 511;
  float v;
  if (r < 128) {
    v = xw[(size_t)k * 160 + 32 + r];
  } else {
    int d = r - 128;
    float s = 0.f;
#pragma unroll
    for (int j = 0; j < DTR; ++j) s += xw[(size_t)k * 160 + j] * dw[(size_t)j * DM + d];
    v = s;
  }
  u16 h = f2bf(v);
  Wt_hi[idx] = h;
  Wt_lo[idx] = f2bf(v - bf2f(h));
}

__global__ __launch_bounds__(256) void bias_combine_kernel(
    const float* __restrict__ xb, const float* __restrict__ dw,
    const float* __restrict__ db, float* __restrict__ bias_c) {
  int r = blockIdx.x * 256 + threadIdx.x;
  if (r >= 640) return;
  float v;
  if (r < 128) {
    v = xb[32 + r];
  } else {
    int d = r - 128;
    float s = db[d];
#pragma unroll
    for (int j = 0; j < DTR; ++j) s += xb[j] * dw[(size_t)j * DM + d];
    v = s;
  }
  bias_c[r] = v;
}

// ---------------------------------------------------------------------------
// in_proj resident-weight split-bf16 MFMA GEMM (NEW this round — replaces the
// 2-barrier mfma_split_gemm whose 1 block/CU barrier-drain stall cost ~45 us;
// same pathology measured at R4/R5). C[4096][1024] = A@W + b.
// Block = 128 rows x 64 cols, 4 waves 2x2; B-panel (hi+lo, 128 KB) staged
// ONCE; A streams from global (L2-resident); ZERO barriers in the K-loop.
// ---------------------------------------------------------------------------
__global__ __launch_bounds__(256) void in_proj_resident_kernel(
    const u16* __restrict__ A_hi, const u16* __restrict__ A_lo,
    const u16* __restrict__ Bt_hi, const u16* __restrict__ Bt_lo,
    const float* __restrict__ bias, float* __restrict__ C) {
  __shared__ alignas(16) u16 sBh[64 * 512];  // 64 KB
  __shared__ alignas(16) u16 sBl[64 * 512];  // 64 KB

  const int lane = threadIdx.x & 63;
  const int wv = threadIdx.x >> 6;
  const int wr = wv >> 1;
  const int wc = wv & 1;
  const int bm = blockIdx.y * 128;
  const int bn = blockIdx.x * 64;
  const int fr = lane & 15;
  const int q = lane >> 4;

  {
    const int r0 = wv * 16;
#pragma unroll
    for (int i = 0; i < 16; ++i) {
      int r = r0 + i;
      size_t g = (size_t)(bn + r) * 512 + (size_t)(lane ^ (r & 7)) * 8;
      gload_lds16(Bt_hi + g, sBh + r * 512);
      gload_lds16(Bt_lo + g, sBl + r * 512);
    }
  }
  __syncthreads();  // B panel resident for the whole kernel

  size_t arow[4];
#pragma unroll
  for (int mi = 0; mi < 4; ++mi)
    arow[mi] = (size_t)(bm + wr * 64 + mi * 16 + fr) * 512;
  int bcol[2];
#pragma unroll
  for (int nj = 0; nj < 2; ++nj) bcol[nj] = wc * 32 + nj * 16 + fr;

  f32x4 zero = {0.f, 0.f, 0.f, 0.f};
  f32x4 acc[4][2];
#pragma unroll
  for (int i = 0; i < 4; ++i) {
    acc[i][0] = zero;
    acc[i][1] = zero;
  }

#pragma unroll 4
  for (int kt = 0; kt < 16; ++kt) {
    bf16x8 ah[4], al[4], bh[2], bl[2];
    const int kc = kt * 4 + q;
#pragma unroll
    for (int nj = 0; nj < 2; ++nj) {
      int off = bcol[nj] * 512 + ((kc ^ (bcol[nj] & 7)) * 8);
      bh[nj] = *(const bf16x8*)(sBh + off);
      bl[nj] = *(const bf16x8*)(sBl + off);
    }
#pragma unroll
    for (int mi = 0; mi < 4; ++mi) {
      size_t ga = arow[mi] + kt * 32 + q * 8;
      ah[mi] = *(const bf16x8*)(A_hi + ga);
      al[mi] = *(const bf16x8*)(A_lo + ga);
    }
#pragma unroll
    for (int mi = 0; mi < 4; ++mi)
#pragma unroll
      for (int nj = 0; nj < 2; ++nj) {
        f32x4 a = acc[mi][nj];
        a = __builtin_amdgcn_mfma_f32_16x16x32_bf16(al[mi], bh[nj], a, 0, 0, 0);
        a = __builtin_amdgcn_mfma_f32_16x16x32_bf16(ah[mi], bl[nj], a, 0, 0, 0);
        a = __builtin_amdgcn_mfma_f32_16x16x32_bf16(ah[mi], bh[nj], a, 0, 0, 0);
        acc[mi][nj] = a;
      }
  }

#pragma unroll
  for (int mi = 0; mi < 4; ++mi) {
#pragma unroll
    for (int nj = 0; nj < 2; ++nj) {
      int row = bm + wr * 64 + mi * 16 + q * 4;
      int col = bn + wc * 32 + nj * 16 + fr;
      float bs = bias[col];
#pragma unroll
      for (int e = 0; e < 4; ++e)
        C[(size_t)(row + e) * 1024 + col] = acc[mi][nj][e] + bs;
    }
  }
}

// ---------------------------------------------------------------------------
// xpd GEMM, resident-weight variant (byte-identical to R11): trans-unit
// softplus fused for cols >= 128.
// ---------------------------------------------------------------------------
__global__ __launch_bounds__(256) void xpd_gemm_kernel(
    const u16* __restrict__ A_hi, const u16* __restrict__ A_lo,
    const u16* __restrict__ Bt_hi, const u16* __restrict__ Bt_lo,
    const float* __restrict__ bias, float* __restrict__ C) {
  __shared__ alignas(16) u16 sBh[64 * 512];  // 64 KB
  __shared__ alignas(16) u16 sBl[64 * 512];  // 64 KB

  const int lane = threadIdx.x & 63;
  const int wv = threadIdx.x >> 6;
  const int wr = wv >> 1;
  const int wc = wv & 1;
  const int bm = blockIdx.y * 128;
  const int bn = blockIdx.x * 64;
  const int fr = lane & 15;
  const int q = lane >> 4;

  {
    const int r0 = wv * 16;
#pragma unroll
    for (int i = 0; i < 16; ++i) {
      int r = r0 + i;
      size_t g = (size_t)(bn + r) * 512 + (size_t)(lane ^ (r & 7)) * 8;
      gload_lds16(Bt_hi + g, sBh + r * 512);
      gload_lds16(Bt_lo + g, sBl + r * 512);
    }
  }
  __syncthreads();  // B panel resident for the whole kernel

  size_t arow[4];
#pragma unroll
  for (int mi = 0; mi < 4; ++mi)
    arow[mi] = (size_t)(bm + wr * 64 + mi * 16 + fr) * 512;
  int bcol[2];
#pragma unroll
  for (int nj = 0; nj < 2; ++nj) bcol[nj] = wc * 32 + nj * 16 + fr;

  f32x4 zero = {0.f, 0.f, 0.f, 0.f};
  f32x4 acc[4][2];
#pragma unroll
  for (int i = 0; i < 4; ++i) {
    acc[i][0] = zero;
    acc[i][1] = zero;
  }

#pragma unroll 4
  for (int kt = 0; kt < 16; ++kt) {
    bf16x8 ah[4], al[4], bh[2], bl[2];
    const int kc = kt * 4 + q;
#pragma unroll
    for (int nj = 0; nj < 2; ++nj) {
      int off = bcol[nj] * 512 + ((kc ^ (bcol[nj] & 7)) * 8);
      bh[nj] = *(const bf16x8*)(sBh + off);
      bl[nj] = *(const bf16x8*)(sBl + off);
    }
#pragma unroll
    for (int mi = 0; mi < 4; ++mi) {
      size_t ga = arow[mi] + kt * 32 + q * 8;
      ah[mi] = *(const bf16x8*)(A_hi + ga);
      al[mi] = *(const bf16x8*)(A_lo + ga);
    }
#pragma unroll
    for (int mi = 0; mi < 4; ++mi)
#pragma unroll
      for (int nj = 0; nj < 2; ++nj) {
        f32x4 a = acc[mi][nj];
        a = __builtin_amdgcn_mfma_f32_16x16x32_bf16(al[mi], bh[nj], a, 0, 0, 0);
        a = __builtin_amdgcn_mfma_f32_16x16x32_bf16(ah[mi], bl[nj], a, 0, 0, 0);
        a = __builtin_amdgcn_mfma_f32_16x16x32_bf16(ah[mi], bh[nj], a, 0, 0, 0);
        acc[mi][nj] = a;
      }
  }

  const bool act = (bn >= 128);  // block-uniform: dt columns
#pragma unroll
  for (int mi = 0; mi < 4; ++mi) {
#pragma unroll
    for (int nj = 0; nj < 2; ++nj) {
      int row = bm + wr * 64 + mi * 16 + q * 4;
      int col = bn + wc * 32 + nj * 16 + fr;
      float bs = bias[col];
#pragma unroll
      for (int e = 0; e < 4; ++e) {
        float v = acc[mi][nj][e] + bs;
        if (act) {
          // softplus(v) = ln(1+e^v) = ln2 * log2(1 + 2^(v*log2e))
          float sp = 0.6931471806f * LOG2(1.f + EXP2(v * 1.44269504f));
          v = (v > 20.f) ? v : sp;
        }
        C[(size_t)(row + e) * XPD_LD + col] = v;
      }
    }
  }
}

// ---------------------------------------------------------------------------
// Depthwise causal conv1d (K=4) + bf16 hi/lo split, vectorized x4 over d.
// ---------------------------------------------------------------------------
__global__ __launch_bounds__(256) void conv_split_kernel(
    const float* __restrict__ xz, const float* __restrict__ w,
    const float* __restrict__ cb, float* __restrict__ xc,
    u16* __restrict__ hi, u16* __restrict__ lo) {
  int idx4 = blockIdx.x * 256 + threadIdx.x;  // over NROWS*DM/4
  if (idx4 >= NROWS * DM / 4) return;
  const int d0 = (idx4 & (DM / 4 - 1)) * 4;   // 0,4,...,508
  const int row = idx4 >> 7;                  // b*SEQL + t
  const int t = row & (SEQL - 1);

  float4 acc = *(const float4*)(cb + d0);
#pragma unroll
  for (int k = 0; k < DCONV; ++k) {
    int ts = t + k - (DCONV - 1);
    if (ts >= 0) {
      float4 v = *(const float4*)(xz + (size_t)(row + k - (DCONV - 1)) * (2 * DM) + d0);
      acc.x += w[(d0 + 0) * DCONV + k] * v.x;
      acc.y += w[(d0 + 1) * DCONV + k] * v.y;
      acc.z += w[(d0 + 2) * DCONV + k] * v.z;
      acc.w += w[(d0 + 3) * DCONV + k] * v.w;
    }
  }
  size_t o = (size_t)row * DM + d0;
  *(float4*)(xc + o) = acc;
  ushort4 h, l;
  h.x = f2bf(acc.x); l.x = f2bf(acc.x - bf2f(h.x));
  h.y = f2bf(acc.y); l.y = f2bf(acc.y - bf2f(h.y));
  h.z = f2bf(acc.z); l.z = f2bf(acc.z - bf2f(h.z));
  h.w = f2bf(acc.w); l.w = f2bf(acc.w - bf2f(h.w));
  *(ushort4*)(hi + o) = h;
  *(ushort4*)(lo + o) = l;
}

// ---------------------------------------------------------------------------
// Chunked selective scan (byte-identical to R9's — frozen best).
// xpd layout: Bp = col n, Cp = col 64+n, dt = 128+d.
// ---------------------------------------------------------------------------
__global__ __launch_bounds__(256) void scan_phase1(
    const float* __restrict__ xpd, const float* __restrict__ xc,
    const float* __restrict__ A_log, const float* __restrict__ Bpar,
    float* __restrict__ hout, float* __restrict__ sdt_arr) {
  const int lane = threadIdx.x & 63;
  const int wid = (blockIdx.x << 2) + (threadIdx.x >> 6);  // ch*NC + c
  const int ch = wid >> 5;
  const int c = wid & (NC - 1);
  const int b = ch >> 9;
  const int d = ch & (DM - 1);
  const int n = lane;

  const float aq = -__expf(A_log[d * DST + n]) * 1.44269504f;
  const float bpn = Bpar[d * DST + n];
  float h = 0.f, sdt = 0.f;

  const size_t row0 = (size_t)b * SEQL + (size_t)c * CL;
  const float* dtp = xpd + row0 * XPD_LD + 128 + d;
  const float* up = xc + row0 * DM + d;
  const float* bp = xpd + row0 * XPD_LD + n;

  for (int t0 = 0; t0 < CL; t0 += 4) {
    float dtv[4], uv[4], bpt[4];
#pragma unroll
    for (int j = 0; j < 4; ++j) {
      dtv[j] = dtp[(size_t)(t0 + j) * XPD_LD];
      uv[j] = up[(size_t)(t0 + j) * DM];
      bpt[j] = bp[(size_t)(t0 + j) * XPD_LD];
    }
#pragma unroll
    for (int j = 0; j < 4; ++j) {
      float Ad = EXP2(dtv[j] * aq);
      h = Ad * h + (bpn * bpt[j]) * (dtv[j] * uv[j]);
      sdt += dtv[j];
    }
  }
  hout[(size_t)wid * DST + n] = h;
  if (lane == 0) sdt_arr[wid] = sdt;
}

__global__ __launch_bounds__(256) void scan_phase2(
    const float* __restrict__ A_log, float* __restrict__ hout,
    const float* __restrict__ sdt_arr) {
  const int lane = threadIdx.x & 63;
  const int ch = (blockIdx.x << 2) + (threadIdx.x >> 6);
  const int d = ch & (DM - 1);
  const float aq = -__expf(A_log[d * DST + lane]) * 1.44269504f;

  float tmp[NC], pa[NC];
#pragma unroll
  for (int c = 0; c < NC; ++c) {
    tmp[c] = hout[((size_t)ch * NC + c) * DST + lane];
    pa[c] = EXP2(aq * sdt_arr[ch * NC + c]);
  }
  float h = 0.f;
#pragma unroll
  for (int c = 0; c < NC; ++c) {
    hout[((size_t)ch * NC + c) * DST + lane] = h;
    h = pa[c] * h + tmp[c];
  }
}

__global__ __launch_bounds__(256) void scan_phase3(
    const float* __restrict__ xpd, const float* __restrict__ xc,
    const float* __restrict__ xz,
    const float* __restrict__ A_log, const float* __restrict__ Bpar,
    const float* __restrict__ Cpar, const float* __restrict__ Dpar,
    const float* __restrict__ hin, float* __restrict__ out) {
  __shared__ float W[4][16][68];

  const int lane = threadIdx.x & 63;
  const int wave = threadIdx.x >> 6;
  const int wid = (blockIdx.x << 2) + wave;
  const int ch = wid >> 5;
  const int c = wid & (NC - 1);
  const int b = ch >> 9;
  const int d = ch & (DM - 1);
  const int n = lane;

  const float aq = -__expf(A_log[d * DST + n]) * 1.44269504f;
  const float bpn = Bpar[d * DST + n];
  const float cpn = Cpar[d * DST + n];
  const float Dd = Dpar[d];
  float h = hin[(size_t)wid * DST + n];

  const size_t row0 = (size_t)b * SEQL + (size_t)c * CL;
  const float* dtp = xpd + row0 * XPD_LD + 128 + d;
  const float* up = xc + row0 * DM + d;
  const float* bp = xpd + row0 * XPD_LD + n;
  const float* cp = xpd + row0 * XPD_LD + 64 + n;

  const int tt = lane & 15;
  const int q = lane >> 4;

  for (int t0 = 0; t0 < CL; t0 += 16) {
#pragma unroll
    for (int g = 0; g < 16; g += 4) {
      float dtv[4], uv[4], bpt[4], cpt[4];
#pragma unroll
      for (int j = 0; j < 4; ++j) {
        size_t t = (size_t)(t0 + g + j);
        dtv[j] = dtp[t * XPD_LD];
        uv[j] = up[t * DM];
        bpt[j] = bp[t * XPD_LD];
        cpt[j] = cp[t * XPD_LD];
      }
#pragma unroll
      for (int j = 0; j < 4; ++j) {
        float Ad = EXP2(dtv[j] * aq);
        h = Ad * h + (bpn * bpt[j]) * (dtv[j] * uv[j]);
        W[wave][g + j][n] = (cpn * cpt[j]) * h;
      }
    }
    const float4* wr = (const float4*)&W[wave][tt][q * 16];
    float s = 0.f;
#pragma unroll
    for (int k2 = 0; k2 < 4; ++k2) {
      float4 v = wr[k2];
      s += (v.x + v.y) + (v.z + v.w);
    }
    s += __shfl_xor(s, 16, 64);
    s += __shfl_xor(s, 32, 64);
    if (lane < 16) {
      size_t t = (size_t)(t0 + lane);
      float u = up[t * DM];
      float zz = xz[(row0 + t) * (2 * DM) + DM + d];
      float y = s + Dd * u;
      float sil = zz / (1.f + __expf(-zz));
      out[(row0 + t) * DM + d] = y * sil;
    }
  }
}

// ---------------------------------------------------------------------------
extern "C" void kernel_launch(void* const* d_in, const int* in_sizes, int n_in,
                              void* d_out, int out_size, void* d_ws,
                              size_t ws_size, hipStream_t stream) {
  const float* x = (const float*)d_in[0];           // [B,L,DM]
  const float* in_proj_w = (const float*)d_in[1];   // [DM, 2DM]
  const float* in_proj_b = (const float*)d_in[2];   // [2DM]
  const float* conv_w = (const float*)d_in[3];      // [DM,1,4]
  const float* conv_b = (const float*)d_in[4];      // [DM]
  const float* x_proj_w = (const float*)d_in[5];    // [DM, 160]
  const float* x_proj_b = (const float*)d_in[6];    // [160]
  const float* dt_proj_w = (const float*)d_in[7];   // [32, DM]
  const float* dt_proj_b = (const float*)d_in[8];   // [DM]
  const float* A_log = (const float*)d_in[9];       // [DM, DST]
  const float* B_param = (const float*)d_in[10];    // [DM, DST]
  const float* C_param = (const float*)d_in[11];    // [DM, DST]
  const float* D_param = (const float*)d_in[12];    // [DM]
  float* out = (float*)d_out;

  // Workspace partition (~56 MB total) — R5/R9 layout.
  float* ws = (float*)d_ws;
  float* xz = ws;                            // NROWS*2DM   = 4,194,304 f
  float* xc = xz + (size_t)NROWS * 2 * DM;   // NROWS*DM    = 2,097,152 f
  float* xpd = xc + (size_t)NROWS * DM;      // NROWS*640   = 2,621,440 f
  float* hout = xpd + (size_t)NROWS * XPD_LD;  // 2,097,152 f
  float* sdt = hout + (size_t)BSZ * DM * NC * DST;  // 32,768 f
  float* bias_c = sdt + (size_t)BSZ * DM * NC;      // 640 f
  u16* A_hi = (u16*)(bias_c + 1024);         // 2,097,152 u16
  u16* A_lo = A_hi + (size_t)NROWS * DM;     // 2,097,152 u16
  u16* Wt_in_hi = A_lo + (size_t)NROWS * DM; // 1024*512 u16
  u16* Wt_in_lo = Wt_in_hi + (size_t)1024 * 512;
  u16* Wt_c_hi = Wt_in_lo + (size_t)1024 * 512;  // 640*512 u16
  u16* Wt_c_lo = Wt_c_hi + (size_t)640 * 512;

  // 0) operand prep: splits + combined projection weight/bias
  hipLaunchKernelGGL(split_x_kernel, dim3((NROWS * DM) / (256 * 4)), dim3(256),
                     0, stream, x, A_hi, A_lo);
  hipLaunchKernelGGL(split_w_kernel, dim3(32, 16), dim3(256), 0, stream,
                     in_proj_w, Wt_in_hi, Wt_in_lo);
  hipLaunchKernelGGL(w_combine_kernel, dim3((640 * 512) / 256), dim3(256), 0,
                     stream, x_proj_w, dt_proj_w, Wt_c_hi, Wt_c_lo);
  hipLaunchKernelGGL(bias_combine_kernel, dim3(3), dim3(256), 0, stream,
                     x_proj_b, dt_proj_w, dt_proj_b, bias_c);

  // 1) in_proj via resident-weight barrier-free MFMA GEMM (512 blocks)
  hipLaunchKernelGGL(in_proj_resident_kernel, dim3(1024 / 64, NROWS / 128),
                     dim3(256), 0, stream, A_hi, A_lo, Wt_in_hi, Wt_in_lo,
                     in_proj_b, xz);

  // 2) depthwise causal conv + bf16 split of xc (vectorized x4)
  hipLaunchKernelGGL(conv_split_kernel, dim3((NROWS * DM / 4 + 255) / 256),
                     dim3(256), 0, stream, xz, conv_w, conv_b, xc, A_hi, A_lo);

  // 3) fused x_proj+dt_proj via resident GEMM, trans-unit softplus fused
  hipLaunchKernelGGL(xpd_gemm_kernel, dim3(640 / 64, NROWS / 128),
                     dim3(256), 0, stream, A_hi, A_lo, Wt_c_hi, Wt_c_lo,
                     bias_c, xpd);

  // 4) chunked selective scan (R9-frozen)
  {
    dim3 grid((BSZ * DM * NC) / 4);  // 8192 blocks, 4 waves each
    hipLaunchKernelGGL(scan_phase1, grid, dim3(256), 0, stream,
                       xpd, xc, A_log, B_param, hout, sdt);
    hipLaunchKernelGGL(scan_phase2, dim3((BSZ * DM) / 4), dim3(256), 0, stream,
                       A_log, hout, sdt);
    hipLaunchKernelGGL(scan_phase3, grid, dim3(256), 0, stream,
                       xpd, xc, xz, A_log, B_param, C_param, D_param,
                       hout, out);
  }
}

// Round 14
// 247.507 us; speedup vs baseline: 1.0723x; 1.0723x over previous
//
#include <hip/hip_runtime.h>
#include <hip/hip_bf16.h>

// Problem constants (StateSpaceLayer): B=2, L=2048, D_MODEL=512, D_STATE=64,
// D_CONV=4, DT_RANK=32. All inputs/outputs fp32.
#define BSZ 2
#define SEQL 2048
#define DM 512
#define DST 64
#define DCONV 4
#define DTR 32
#define NROWS (BSZ * SEQL)   // 4096 flattened (b, t) rows

// Chunked scan decomposition
#define NC 32   // chunks per sequence
#define CL 64   // chunk length (NC*CL == SEQL)

// Combined projection output layout: xpd[row][640]
//   cols [0,64) = Bp, cols [64,128) = Cp, cols [128,640) = softplus(dt)
#define XPD_LD 640

typedef unsigned short u16;
typedef short bf16x8 __attribute__((ext_vector_type(8)));
typedef float f32x4 __attribute__((ext_vector_type(4)));

// Raw v_exp_f32 (2^x) / v_log_f32 (log2 x) without OCML fixup chains.
#if __has_builtin(__builtin_amdgcn_exp2f)
#define EXP2(x) __builtin_amdgcn_exp2f(x)
#else
#define EXP2(x) exp2f(x)
#endif
#if __has_builtin(__builtin_amdgcn_logf)
#define LOG2(x) __builtin_amdgcn_logf(x)
#else
#define LOG2(x) log2f(x)
#endif

// fp32 -> bf16 RNE split helpers (bit ops)
__device__ __forceinline__ u16 f2bf(float f) {
  unsigned u = __float_as_uint(f);
  return (u16)((u + 0x7FFFu + ((u >> 16) & 1u)) >> 16);
}
__device__ __forceinline__ float bf2f(u16 h) {
  return __uint_as_float(((unsigned)h) << 16);
}

// async global->LDS, 16B per lane (dest = wave-uniform base + lane*16)
__device__ __forceinline__ void gload_lds16(const u16* g, u16* l) {
  __builtin_amdgcn_global_load_lds(
      (const __attribute__((address_space(1))) void*)(const void*)g,
      (__attribute__((address_space(3))) void*)(void*)l, 16, 0, 0);
}

// ---------------------------------------------------------------------------
// Split conversion kernels.
// ---------------------------------------------------------------------------
__global__ __launch_bounds__(256) void split_x_kernel(
    const float* __restrict__ x, u16* __restrict__ hi, u16* __restrict__ lo) {
  int idx = (blockIdx.x * 256 + threadIdx.x) * 4;  // over NROWS*DM
  float4 v = *(const float4*)(x + idx);
  ushort4 h, l;
  h.x = f2bf(v.x); l.x = f2bf(v.x - bf2f(h.x));
  h.y = f2bf(v.y); l.y = f2bf(v.y - bf2f(h.y));
  h.z = f2bf(v.z); l.z = f2bf(v.z - bf2f(h.z));
  h.w = f2bf(v.w); l.w = f2bf(v.w - bf2f(h.w));
  *(ushort4*)(hi + idx) = h;
  *(ushort4*)(lo + idx) = l;
}

__global__ __launch_bounds__(256) void split_w_kernel(
    const float* __restrict__ W, u16* __restrict__ Wt_hi,
    u16* __restrict__ Wt_lo) {
  __shared__ u16 shi[32][33], slo[32][33];
  const int n0 = blockIdx.x * 32;  // 32 blocks over N=1024
  const int k0 = blockIdx.y * 32;  // 16 blocks over K=512
  const int i = threadIdx.x >> 5;  // 0..7
  const int j = threadIdx.x & 31;
#pragma unroll
  for (int r = 0; r < 4; ++r) {
    int k = i + r * 8;
    float v = W[(size_t)(k0 + k) * 1024 + n0 + j];
    u16 h = f2bf(v);
    shi[k][j] = h;
    slo[k][j] = f2bf(v - bf2f(h));
  }
  __syncthreads();
#pragma unroll
  for (int r = 0; r < 4; ++r) {
    int n = i + r * 8;  // row of Wt within tile
    Wt_hi[(size_t)(n0 + n) * 512 + k0 + j] = shi[j][n];
    Wt_lo[(size_t)(n0 + n) * 512 + k0 + j] = slo[j][n];
  }
}

// ---------------------------------------------------------------------------
// Combined projection weight: Wt_c [640][512] bf16 split, transposed.
//   row r<128:  Wt_c[r][k] = x_proj_w[k][32+r]                 (Bp/Cp cols)
//   row 128+d:  Wt_c[128+d][k] = sum_j x_proj_w[k][j]*dt_proj_w[j][d], j<32
// ---------------------------------------------------------------------------
__global__ __launch_bounds__(256) void w_combine_kernel(
    const float* __restrict__ xw, const float* __restrict__ dw,
    u16* __restrict__ Wt_hi, u16* __restrict__ Wt_lo) {
  int idx = blockIdx.x * 256 + threadIdx.x;  // over 640*512
  int r = idx >> 9;
  int k = idx & 511;
  float v;
  if (r < 128) {
    v = xw[(size_t)k * 160 + 32 + r];
  } else {
    int d = r - 128;
    float s = 0.f;
#pragma unroll
    for (int j = 0; j < DTR; ++j) s += xw[(size_t)k * 160 + j] * dw[(size_t)j * DM + d];
    v = s;
  }
  u16 h = f2bf(v);
  Wt_hi[idx] = h;
  Wt_lo[idx] = f2bf(v - bf2f(h));
}

__global__ __launch_bounds__(256) void bias_combine_kernel(
    const float* __restrict__ xb, const float* __restrict__ dw,
    const float* __restrict__ db, float* __restrict__ bias_c) {
  int r = blockIdx.x * 256 + threadIdx.x;
  if (r >= 640) return;
  float v;
  if (r < 128) {
    v = xb[32 + r];
  } else {
    int d = r - 128;
    float s = db[d];
#pragma unroll
    for (int j = 0; j < DTR; ++j) s += xb[j] * dw[(size_t)j * DM + d];
    v = s;
  }
  bias_c[r] = v;
}

// ---------------------------------------------------------------------------
// in_proj split-bf16 MFMA GEMM (R9/R11 version — A/B-verified faster than the
// resident variant here: 256 blocks = 1 block/CU with ALL CUs occupied, vs
// resident's 512 blocks = 2 rounds of 128KB-LDS staging. R12 measured +18 us
// for resident). C[4096][1024] = Ah@Wh + Ah@Wl + Al@Wh + bias.
// ---------------------------------------------------------------------------
__global__ __launch_bounds__(256) void mfma_split_gemm(
    const u16* __restrict__ A_hi, const u16* __restrict__ A_lo,
    const u16* __restrict__ Bt_hi, const u16* __restrict__ Bt_lo,
    const float* __restrict__ bias, float* __restrict__ C) {
  __shared__ alignas(16) u16 sAh[4096], sAl[4096], sBh[4096], sBl[4096];

  const int lane = threadIdx.x & 63;
  const int wv = threadIdx.x >> 6;
  const int bm = blockIdx.y * 128;
  const int bn = blockIdx.x * 128;
  const int fr = lane & 15;
  const int q = lane >> 4;

  const int st_rowc = lane >> 2;
  const int st_qd = lane & 3;

  const bf16x8 *pAh[4], *pAl[4], *pBh[4], *pBl[4];
#pragma unroll
  for (int t = 0; t < 4; ++t) {
    int ra = (wv >> 1) * 64 + t * 16 + fr;
    int ea = ra * 32 + ((q ^ ((ra >> 1) & 3)) * 8);
    pAh[t] = (const bf16x8*)(sAh + ea);
    pAl[t] = (const bf16x8*)(sAl + ea);
    int rb = (wv & 1) * 64 + t * 16 + fr;
    int eb = rb * 32 + ((q ^ ((rb >> 1) & 3)) * 8);
    pBh[t] = (const bf16x8*)(sBh + eb);
    pBl[t] = (const bf16x8*)(sBl + eb);
  }

  f32x4 zero = {0.f, 0.f, 0.f, 0.f};
  f32x4 acc[4][4];
#pragma unroll
  for (int i = 0; i < 4; ++i)
#pragma unroll
    for (int j = 0; j < 4; ++j) acc[i][j] = zero;

  auto stage = [&](int k0) {
#pragma unroll
    for (int i = 0; i < 2; ++i) {
      int c = wv + i * 4;
      int row = c * 16 + st_rowc;
      int qs = st_qd ^ ((row >> 1) & 3);
      size_t ga = (size_t)(bm + row) * 512 + k0 + qs * 8;
      size_t gb = (size_t)(bn + row) * 512 + k0 + qs * 8;
      gload_lds16(A_hi + ga, sAh + c * 512);
      gload_lds16(A_lo + ga, sAl + c * 512);
      gload_lds16(Bt_hi + gb, sBh + c * 512);
      gload_lds16(Bt_lo + gb, sBl + c * 512);
    }
  };

  stage(0);
  for (int kt = 0; kt < 16; ++kt) {
    __syncthreads();
    bf16x8 ah[4], al[4], bh[4], bl[4];
#pragma unroll
    for (int t = 0; t < 4; ++t) {
      ah[t] = *pAh[t];
      al[t] = *pAl[t];
      bh[t] = *pBh[t];
      bl[t] = *pBl[t];
    }
    __syncthreads();
    if (kt < 15) stage((kt + 1) * 32);
#pragma unroll
    for (int mi = 0; mi < 4; ++mi)
#pragma unroll
      for (int nj = 0; nj < 4; ++nj) {
        f32x4 a = acc[mi][nj];
        a = __builtin_amdgcn_mfma_f32_16x16x32_bf16(al[mi], bh[nj], a, 0, 0, 0);
        a = __builtin_amdgcn_mfma_f32_16x16x32_bf16(ah[mi], bl[nj], a, 0, 0, 0);
        a = __builtin_amdgcn_mfma_f32_16x16x32_bf16(ah[mi], bh[nj], a, 0, 0, 0);
        acc[mi][nj] = a;
      }
  }

#pragma unroll
  for (int mi = 0; mi < 4; ++mi) {
#pragma unroll
    for (int nj = 0; nj < 4; ++nj) {
      int row = bm + (wv >> 1) * 64 + mi * 16 + q * 4;
      int col = bn + (wv & 1) * 64 + nj * 16 + fr;
      float bs = bias[col];
#pragma unroll
      for (int e = 0; e < 4; ++e)
        C[(size_t)(row + e) * 1024 + col] = acc[mi][nj][e] + bs;
    }
  }
}

// ---------------------------------------------------------------------------
// xpd GEMM, resident-weight variant (R11): trans-unit softplus fused for
// cols >= 128 (2 trans + 2 mul — NOT libm, whose ~40-inst tail at 1 block/CU
// cost 73 us in R10).
// ---------------------------------------------------------------------------
__global__ __launch_bounds__(256) void xpd_gemm_kernel(
    const u16* __restrict__ A_hi, const u16* __restrict__ A_lo,
    const u16* __restrict__ Bt_hi, const u16* __restrict__ Bt_lo,
    const float* __restrict__ bias, float* __restrict__ C) {
  __shared__ alignas(16) u16 sBh[64 * 512];  // 64 KB
  __shared__ alignas(16) u16 sBl[64 * 512];  // 64 KB

  const int lane = threadIdx.x & 63;
  const int wv = threadIdx.x >> 6;
  const int wr = wv >> 1;
  const int wc = wv & 1;
  const int bm = blockIdx.y * 128;
  const int bn = blockIdx.x * 64;
  const int fr = lane & 15;
  const int q = lane >> 4;

  {
    const int r0 = wv * 16;
#pragma unroll
    for (int i = 0; i < 16; ++i) {
      int r = r0 + i;
      size_t g = (size_t)(bn + r) * 512 + (size_t)(lane ^ (r & 7)) * 8;
      gload_lds16(Bt_hi + g, sBh + r * 512);
      gload_lds16(Bt_lo + g, sBl + r * 512);
    }
  }
  __syncthreads();  // B panel resident for the whole kernel

  size_t arow[4];
#pragma unroll
  for (int mi = 0; mi < 4; ++mi)
    arow[mi] = (size_t)(bm + wr * 64 + mi * 16 + fr) * 512;
  int bcol[2];
#pragma unroll
  for (int nj = 0; nj < 2; ++nj) bcol[nj] = wc * 32 + nj * 16 + fr;

  f32x4 zero = {0.f, 0.f, 0.f, 0.f};
  f32x4 acc[4][2];
#pragma unroll
  for (int i = 0; i < 4; ++i) {
    acc[i][0] = zero;
    acc[i][1] = zero;
  }

#pragma unroll 4
  for (int kt = 0; kt < 16; ++kt) {
    bf16x8 ah[4], al[4], bh[2], bl[2];
    const int kc = kt * 4 + q;
#pragma unroll
    for (int nj = 0; nj < 2; ++nj) {
      int off = bcol[nj] * 512 + ((kc ^ (bcol[nj] & 7)) * 8);
      bh[nj] = *(const bf16x8*)(sBh + off);
      bl[nj] = *(const bf16x8*)(sBl + off);
    }
#pragma unroll
    for (int mi = 0; mi < 4; ++mi) {
      size_t ga = arow[mi] + kt * 32 + q * 8;
      ah[mi] = *(const bf16x8*)(A_hi + ga);
      al[mi] = *(const bf16x8*)(A_lo + ga);
    }
#pragma unroll
    for (int mi = 0; mi < 4; ++mi)
#pragma unroll
      for (int nj = 0; nj < 2; ++nj) {
        f32x4 a = acc[mi][nj];
        a = __builtin_amdgcn_mfma_f32_16x16x32_bf16(al[mi], bh[nj], a, 0, 0, 0);
        a = __builtin_amdgcn_mfma_f32_16x16x32_bf16(ah[mi], bl[nj], a, 0, 0, 0);
        a = __builtin_amdgcn_mfma_f32_16x16x32_bf16(ah[mi], bh[nj], a, 0, 0, 0);
        acc[mi][nj] = a;
      }
  }

  const bool act = (bn >= 128);  // block-uniform: dt columns
#pragma unroll
  for (int mi = 0; mi < 4; ++mi) {
#pragma unroll
    for (int nj = 0; nj < 2; ++nj) {
      int row = bm + wr * 64 + mi * 16 + q * 4;
      int col = bn + wc * 32 + nj * 16 + fr;
      float bs = bias[col];
#pragma unroll
      for (int e = 0; e < 4; ++e) {
        float v = acc[mi][nj][e] + bs;
        if (act) {
          // softplus(v) = ln(1+e^v) = ln2 * log2(1 + 2^(v*log2e))
          float sp = 0.6931471806f * LOG2(1.f + EXP2(v * 1.44269504f));
          v = (v > 20.f) ? v : sp;
        }
        C[(size_t)(row + e) * XPD_LD + col] = v;
      }
    }
  }
}

// ---------------------------------------------------------------------------
// Depthwise causal conv1d (K=4) + bf16 hi/lo split, vectorized x4 over d.
// ---------------------------------------------------------------------------
__global__ __launch_bounds__(256) void conv_split_kernel(
    const float* __restrict__ xz, const float* __restrict__ w,
    const float* __restrict__ cb, float* __restrict__ xc,
    u16* __restrict__ hi, u16* __restrict__ lo) {
  int idx4 = blockIdx.x * 256 + threadIdx.x;  // over NROWS*DM/4
  if (idx4 >= NROWS * DM / 4) return;
  const int d0 = (idx4 & (DM / 4 - 1)) * 4;   // 0,4,...,508
  const int row = idx4 >> 7;                  // b*SEQL + t
  const int t = row & (SEQL - 1);

  float4 acc = *(const float4*)(cb + d0);
#pragma unroll
  for (int k = 0; k < DCONV; ++k) {
    int ts = t + k - (DCONV - 1);
    if (ts >= 0) {
      float4 v = *(const float4*)(xz + (size_t)(row + k - (DCONV - 1)) * (2 * DM) + d0);
      acc.x += w[(d0 + 0) * DCONV + k] * v.x;
      acc.y += w[(d0 + 1) * DCONV + k] * v.y;
      acc.z += w[(d0 + 2) * DCONV + k] * v.z;
      acc.w += w[(d0 + 3) * DCONV + k] * v.w;
    }
  }
  size_t o = (size_t)row * DM + d0;
  *(float4*)(xc + o) = acc;
  ushort4 h, l;
  h.x = f2bf(acc.x); l.x = f2bf(acc.x - bf2f(h.x));
  h.y = f2bf(acc.y); l.y = f2bf(acc.y - bf2f(h.y));
  h.z = f2bf(acc.z); l.z = f2bf(acc.z - bf2f(h.z));
  h.w = f2bf(acc.w); l.w = f2bf(acc.w - bf2f(h.w));
  *(ushort4*)(hi + o) = h;
  *(ushort4*)(lo + o) = l;
}

// ---------------------------------------------------------------------------
// Chunked selective scan (byte-identical to R9's — frozen best).
// xpd layout: Bp = col n, Cp = col 64+n, dt = 128+d.
// ---------------------------------------------------------------------------
__global__ __launch_bounds__(256) void scan_phase1(
    const float* __restrict__ xpd, const float* __restrict__ xc,
    const float* __restrict__ A_log, const float* __restrict__ Bpar,
    float* __restrict__ hout, float* __restrict__ sdt_arr) {
  const int lane = threadIdx.x & 63;
  const int wid = (blockIdx.x << 2) + (threadIdx.x >> 6);  // ch*NC + c
  const int ch = wid >> 5;
  const int c = wid & (NC - 1);
  const int b = ch >> 9;
  const int d = ch & (DM - 1);
  const int n = lane;

  const float aq = -__expf(A_log[d * DST + n]) * 1.44269504f;
  const float bpn = Bpar[d * DST + n];
  float h = 0.f, sdt = 0.f;

  const size_t row0 = (size_t)b * SEQL + (size_t)c * CL;
  const float* dtp = xpd + row0 * XPD_LD + 128 + d;
  const float* up = xc + row0 * DM + d;
  const float* bp = xpd + row0 * XPD_LD + n;

  for (int t0 = 0; t0 < CL; t0 += 4) {
    float dtv[4], uv[4], bpt[4];
#pragma unroll
    for (int j = 0; j < 4; ++j) {
      dtv[j] = dtp[(size_t)(t0 + j) * XPD_LD];
      uv[j] = up[(size_t)(t0 + j) * DM];
      bpt[j] = bp[(size_t)(t0 + j) * XPD_LD];
    }
#pragma unroll
    for (int j = 0; j < 4; ++j) {
      float Ad = EXP2(dtv[j] * aq);
      h = Ad * h + (bpn * bpt[j]) * (dtv[j] * uv[j]);
      sdt += dtv[j];
    }
  }
  hout[(size_t)wid * DST + n] = h;
  if (lane == 0) sdt_arr[wid] = sdt;
}

__global__ __launch_bounds__(256) void scan_phase2(
    const float* __restrict__ A_log, float* __restrict__ hout,
    const float* __restrict__ sdt_arr) {
  const int lane = threadIdx.x & 63;
  const int ch = (blockIdx.x << 2) + (threadIdx.x >> 6);
  const int d = ch & (DM - 1);
  const float aq = -__expf(A_log[d * DST + lane]) * 1.44269504f;

  float tmp[NC], pa[NC];
#pragma unroll
  for (int c = 0; c < NC; ++c) {
    tmp[c] = hout[((size_t)ch * NC + c) * DST + lane];
    pa[c] = EXP2(aq * sdt_arr[ch * NC + c]);
  }
  float h = 0.f;
#pragma unroll
  for (int c = 0; c < NC; ++c) {
    hout[((size_t)ch * NC + c) * DST + lane] = h;
    h = pa[c] * h + tmp[c];
  }
}

__global__ __launch_bounds__(256) void scan_phase3(
    const float* __restrict__ xpd, const float* __restrict__ xc,
    const float* __restrict__ xz,
    const float* __restrict__ A_log, const float* __restrict__ Bpar,
    const float* __restrict__ Cpar, const float* __restrict__ Dpar,
    const float* __restrict__ hin, float* __restrict__ out) {
  __shared__ float W[4][16][68];

  const int lane = threadIdx.x & 63;
  const int wave = threadIdx.x >> 6;
  const int wid = (blockIdx.x << 2) + wave;
  const int ch = wid >> 5;
  const int c = wid & (NC - 1);
  const int b = ch >> 9;
  const int d = ch & (DM - 1);
  const int n = lane;

  const float aq = -__expf(A_log[d * DST + n]) * 1.44269504f;
  const float bpn = Bpar[d * DST + n];
  const float cpn = Cpar[d * DST + n];
  const float Dd = Dpar[d];
  float h = hin[(size_t)wid * DST + n];

  const size_t row0 = (size_t)b * SEQL + (size_t)c * CL;
  const float* dtp = xpd + row0 * XPD_LD + 128 + d;
  const float* up = xc + row0 * DM + d;
  const float* bp = xpd + row0 * XPD_LD + n;
  const float* cp = xpd + row0 * XPD_LD + 64 + n;

  const int tt = lane & 15;
  const int q = lane >> 4;

  for (int t0 = 0; t0 < CL; t0 += 16) {
#pragma unroll
    for (int g = 0; g < 16; g += 4) {
      float dtv[4], uv[4], bpt[4], cpt[4];
#pragma unroll
      for (int j = 0; j < 4; ++j) {
        size_t t = (size_t)(t0 + g + j);
        dtv[j] = dtp[t * XPD_LD];
        uv[j] = up[t * DM];
        bpt[j] = bp[t * XPD_LD];
        cpt[j] = cp[t * XPD_LD];
      }
#pragma unroll
      for (int j = 0; j < 4; ++j) {
        float Ad = EXP2(dtv[j] * aq);
        h = Ad * h + (bpn * bpt[j]) * (dtv[j] * uv[j]);
        W[wave][g + j][n] = (cpn * cpt[j]) * h;
      }
    }
    const float4* wr = (const float4*)&W[wave][tt][q * 16];
    float s = 0.f;
#pragma unroll
    for (int k2 = 0; k2 < 4; ++k2) {
      float4 v = wr[k2];
      s += (v.x + v.y) + (v.z + v.w);
    }
    s += __shfl_xor(s, 16, 64);
    s += __shfl_xor(s, 32, 64);
    if (lane < 16) {
      size_t t = (size_t)(t0 + lane);
      float u = up[t * DM];
      float zz = xz[(row0 + t) * (2 * DM) + DM + d];
      float y = s + Dd * u;
      float sil = zz / (1.f + __expf(-zz));
      out[(row0 + t) * DM + d] = y * sil;
    }
  }
}

// ---------------------------------------------------------------------------
extern "C" void kernel_launch(void* const* d_in, const int* in_sizes, int n_in,
                              void* d_out, int out_size, void* d_ws,
                              size_t ws_size, hipStream_t stream) {
  const float* x = (const float*)d_in[0];           // [B,L,DM]
  const float* in_proj_w = (const float*)d_in[1];   // [DM, 2DM]
  const float* in_proj_b = (const float*)d_in[2];   // [2DM]
  const float* conv_w = (const float*)d_in[3];      // [DM,1,4]
  const float* conv_b = (const float*)d_in[4];      // [DM]
  const float* x_proj_w = (const float*)d_in[5];    // [DM, 160]
  const float* x_proj_b = (const float*)d_in[6];    // [160]
  const float* dt_proj_w = (const float*)d_in[7];   // [32, DM]
  const float* dt_proj_b = (const float*)d_in[8];   // [DM]
  const float* A_log = (const float*)d_in[9];       // [DM, DST]
  const float* B_param = (const float*)d_in[10];    // [DM, DST]
  const float* C_param = (const float*)d_in[11];    // [DM, DST]
  const float* D_param = (const float*)d_in[12];    // [DM]
  float* out = (float*)d_out;

  // Workspace partition (~56 MB total) — R5/R9 layout.
  float* ws = (float*)d_ws;
  float* xz = ws;                            // NROWS*2DM   = 4,194,304 f
  float* xc = xz + (size_t)NROWS * 2 * DM;   // NROWS*DM    = 2,097,152 f
  float* xpd = xc + (size_t)NROWS * DM;      // NROWS*640   = 2,621,440 f
  float* hout = xpd + (size_t)NROWS * XPD_LD;  // 2,097,152 f
  float* sdt = hout + (size_t)BSZ * DM * NC * DST;  // 32,768 f
  float* bias_c = sdt + (size_t)BSZ * DM * NC;      // 640 f
  u16* A_hi = (u16*)(bias_c + 1024);         // 2,097,152 u16
  u16* A_lo = A_hi + (size_t)NROWS * DM;     // 2,097,152 u16
  u16* Wt_in_hi = A_lo + (size_t)NROWS * DM; // 1024*512 u16
  u16* Wt_in_lo = Wt_in_hi + (size_t)1024 * 512;
  u16* Wt_c_hi = Wt_in_lo + (size_t)1024 * 512;  // 640*512 u16
  u16* Wt_c_lo = Wt_c_hi + (size_t)640 * 512;

  // 0) operand prep: splits + combined projection weight/bias
  hipLaunchKernelGGL(split_x_kernel, dim3((NROWS * DM) / (256 * 4)), dim3(256),
                     0, stream, x, A_hi, A_lo);
  hipLaunchKernelGGL(split_w_kernel, dim3(32, 16), dim3(256), 0, stream,
                     in_proj_w, Wt_in_hi, Wt_in_lo);
  hipLaunchKernelGGL(w_combine_kernel, dim3((640 * 512) / 256), dim3(256), 0,
                     stream, x_proj_w, dt_proj_w, Wt_c_hi, Wt_c_lo);
  hipLaunchKernelGGL(bias_combine_kernel, dim3(3), dim3(256), 0, stream,
                     x_proj_b, dt_proj_w, dt_proj_b, bias_c);

  // 1) in_proj via split-bf16 MFMA (R11 version): xz = x @ in_proj_w + b
  hipLaunchKernelGGL(mfma_split_gemm, dim3(1024 / 128, NROWS / 128),
                     dim3(256), 0, stream, A_hi, A_lo, Wt_in_hi, Wt_in_lo,
                     in_proj_b, xz);

  // 2) depthwise causal conv + bf16 split of xc (vectorized x4)
  hipLaunchKernelGGL(conv_split_kernel, dim3((NROWS * DM / 4 + 255) / 256),
                     dim3(256), 0, stream, xz, conv_w, conv_b, xc, A_hi, A_lo);

  // 3) fused x_proj+dt_proj via resident GEMM, trans-unit softplus fused
  hipLaunchKernelGGL(xpd_gemm_kernel, dim3(640 / 64, NROWS / 128),
                     dim3(256), 0, stream, A_hi, A_lo, Wt_c_hi, Wt_c_lo,
                     bias_c, xpd);

  // 4) chunked selective scan (R9-frozen)
  {
    dim3 grid((BSZ * DM * NC) / 4);  // 8192 blocks, 4 waves each
    hipLaunchKernelGGL(scan_phase1, grid, dim3(256), 0, stream,
                       xpd, xc, A_log, B_param, hout, sdt);
    hipLaunchKernelGGL(scan_phase2, dim3((BSZ * DM) / 4), dim3(256), 0, stream,
                       A_log, hout, sdt);
    hipLaunchKernelGGL(scan_phase3, grid, dim3(256), 0, stream,
                       xpd, xc, xz, A_log, B_param, C_param, D_param,
                       hout, out);
  }
}

// Round 15
// 244.462 us; speedup vs baseline: 1.0856x; 1.0125x over previous
//
#include <hip/hip_runtime.h>
#include <hip/hip_bf16.h>

// Problem constants (StateSpaceLayer): B=2, L=2048, D_MODEL=512, D_STATE=64,
// D_CONV=4, DT_RANK=32. All inputs/outputs fp32.
#define BSZ 2
#define SEQL 2048
#define DM 512
#define DST 64
#define DCONV 4
#define DTR 32
#define NROWS (BSZ * SEQL)   // 4096 flattened (b, t) rows

// Chunked scan decomposition
#define NC 32   // chunks per sequence
#define CL 64   // chunk length (NC*CL == SEQL)

// Combined projection output layout: xpd[row][640]
//   cols [0,64) = Bp, cols [64,128) = Cp, cols [128,640) = softplus(dt)
#define XPD_LD 640

typedef unsigned short u16;
typedef short bf16x8 __attribute__((ext_vector_type(8)));
typedef float f32x4 __attribute__((ext_vector_type(4)));

// Raw v_exp_f32 (2^x) / v_log_f32 (log2 x) without OCML fixup chains.
#if __has_builtin(__builtin_amdgcn_exp2f)
#define EXP2(x) __builtin_amdgcn_exp2f(x)
#else
#define EXP2(x) exp2f(x)
#endif
#if __has_builtin(__builtin_amdgcn_logf)
#define LOG2(x) __builtin_amdgcn_logf(x)
#else
#define LOG2(x) log2f(x)
#endif

// fp32 -> bf16 RNE split helpers (bit ops)
__device__ __forceinline__ u16 f2bf(float f) {
  unsigned u = __float_as_uint(f);
  return (u16)((u + 0x7FFFu + ((u >> 16) & 1u)) >> 16);
}
__device__ __forceinline__ float bf2f(u16 h) {
  return __uint_as_float(((unsigned)h) << 16);
}

// async global->LDS, 16B per lane (dest = wave-uniform base + lane*16)
__device__ __forceinline__ void gload_lds16(const u16* g, u16* l) {
  __builtin_amdgcn_global_load_lds(
      (const __attribute__((address_space(1))) void*)(const void*)g,
      (__attribute__((address_space(3))) void*)(void*)l, 16, 0, 0);
}

// ---------------------------------------------------------------------------
// Split conversion kernels.
// ---------------------------------------------------------------------------
__global__ __launch_bounds__(256) void split_x_kernel(
    const float* __restrict__ x, u16* __restrict__ hi, u16* __restrict__ lo) {
  int idx = (blockIdx.x * 256 + threadIdx.x) * 4;  // over NROWS*DM
  float4 v = *(const float4*)(x + idx);
  ushort4 h, l;
  h.x = f2bf(v.x); l.x = f2bf(v.x - bf2f(h.x));
  h.y = f2bf(v.y); l.y = f2bf(v.y - bf2f(h.y));
  h.z = f2bf(v.z); l.z = f2bf(v.z - bf2f(h.z));
  h.w = f2bf(v.w); l.w = f2bf(v.w - bf2f(h.w));
  *(ushort4*)(hi + idx) = h;
  *(ushort4*)(lo + idx) = l;
}

__global__ __launch_bounds__(256) void split_w_kernel(
    const float* __restrict__ W, u16* __restrict__ Wt_hi,
    u16* __restrict__ Wt_lo) {
  __shared__ u16 shi[32][33], slo[32][33];
  const int n0 = blockIdx.x * 32;  // 32 blocks over N=1024
  const int k0 = blockIdx.y * 32;  // 16 blocks over K=512
  const int i = threadIdx.x >> 5;  // 0..7
  const int j = threadIdx.x & 31;
#pragma unroll
  for (int r = 0; r < 4; ++r) {
    int k = i + r * 8;
    float v = W[(size_t)(k0 + k) * 1024 + n0 + j];
    u16 h = f2bf(v);
    shi[k][j] = h;
    slo[k][j] = f2bf(v - bf2f(h));
  }
  __syncthreads();
#pragma unroll
  for (int r = 0; r < 4; ++r) {
    int n = i + r * 8;  // row of Wt within tile
    Wt_hi[(size_t)(n0 + n) * 512 + k0 + j] = shi[j][n];
    Wt_lo[(size_t)(n0 + n) * 512 + k0 + j] = slo[j][n];
  }
}

// ---------------------------------------------------------------------------
// Combined projection weight: Wt_c [640][512] bf16 split, transposed.
// ---------------------------------------------------------------------------
__global__ __launch_bounds__(256) void w_combine_kernel(
    const float* __restrict__ xw, const float* __restrict__ dw,
    u16* __restrict__ Wt_hi, u16* __restrict__ Wt_lo) {
  int idx = blockIdx.x * 256 + threadIdx.x;  // over 640*512
  int r = idx >> 9;
  int k = idx & 511;
  float v;
  if (r < 128) {
    v = xw[(size_t)k * 160 + 32 + r];
  } else {
    int d = r - 128;
    float s = 0.f;
#pragma unroll
    for (int j = 0; j < DTR; ++j) s += xw[(size_t)k * 160 + j] * dw[(size_t)j * DM + d];
    v = s;
  }
  u16 h = f2bf(v);
  Wt_hi[idx] = h;
  Wt_lo[idx] = f2bf(v - bf2f(h));
}

__global__ __launch_bounds__(256) void bias_combine_kernel(
    const float* __restrict__ xb, const float* __restrict__ dw,
    const float* __restrict__ db, float* __restrict__ bias_c) {
  int r = blockIdx.x * 256 + threadIdx.x;
  if (r >= 640) return;
  float v;
  if (r < 128) {
    v = xb[32 + r];
  } else {
    int d = r - 128;
    float s = db[d];
#pragma unroll
    for (int j = 0; j < DTR; ++j) s += xb[j] * dw[(size_t)j * DM + d];
    v = s;
  }
  bias_c[r] = v;
}

// ---------------------------------------------------------------------------
// in_proj split-bf16 MFMA GEMM, BK=64 variant (R14 change): same 128x128
// 2-barrier skeleton as R11/R13, but 8 K-iterations of BK=64 instead of 16
// of BK=32 -> HALF the barrier-drain events (the measured per-iter cost was
// ~2.8us vs ~0.4us of MFMA work at 1 block/CU). LDS 64KB (grid=256 = 1
// block/CU regardless, so no occupancy cost).
// Swizzle for 128B (bank-aligned) rows: read chunk c' = (kk*4+q) ^ (fr&7);
// stage source chunk (l&7)^(l>>3) — same involution both sides.
// ---------------------------------------------------------------------------
__global__ __launch_bounds__(256) void mfma_split_gemm_bk64(
    const u16* __restrict__ A_hi, const u16* __restrict__ A_lo,
    const u16* __restrict__ Bt_hi, const u16* __restrict__ Bt_lo,
    const float* __restrict__ bias, float* __restrict__ C) {
  __shared__ alignas(16) u16 sAh[8192], sAl[8192], sBh[8192], sBl[8192];

  const int lane = threadIdx.x & 63;
  const int wv = threadIdx.x >> 6;
  const int bm = blockIdx.y * 128;
  const int bn = blockIdx.x * 128;
  const int fr = lane & 15;
  const int q = lane >> 4;       // 16B chunk within a 32-elem substep
  const int sw = fr & 7;         // row-derived swizzle (row&7 == fr&7)

  // Per-tile LDS row bases (elements): row * 64
  int offA[4], offB[4];
#pragma unroll
  for (int t = 0; t < 4; ++t) {
    offA[t] = ((wv >> 1) * 64 + t * 16 + fr) * 64;
    offB[t] = ((wv & 1) * 64 + t * 16 + fr) * 64;
  }

  f32x4 zero = {0.f, 0.f, 0.f, 0.f};
  f32x4 acc[4][4];
#pragma unroll
  for (int i = 0; i < 4; ++i)
#pragma unroll
    for (int j = 0; j < 4; ++j) acc[i][j] = zero;

  // Staging: 16 gloads per array per k-tile (1KB each = 8 rows x 64 k).
  // Wave wv handles gloads g = wv*4 .. wv*4+3 per array.
  // Lane l: dest row g*8 + (l>>3), dest chunk l&7; src chunk (l&7)^(l>>3).
  const int st_r = lane >> 3;      // 0..7 row within gload
  const int st_c = (lane & 7) ^ st_r;  // pre-swizzled source chunk
  auto stage = [&](int k0) {
#pragma unroll
    for (int i = 0; i < 4; ++i) {
      int g = wv * 4 + i;          // 0..15
      int row = g * 8 + st_r;      // 0..127
      size_t ga = (size_t)(bm + row) * 512 + k0 + st_c * 8;
      size_t gb = (size_t)(bn + row) * 512 + k0 + st_c * 8;
      gload_lds16(A_hi + ga, sAh + g * 512);
      gload_lds16(A_lo + ga, sAl + g * 512);
      gload_lds16(Bt_hi + gb, sBh + g * 512);
      gload_lds16(Bt_lo + gb, sBl + g * 512);
    }
  };

  stage(0);
  for (int kt = 0; kt < 8; ++kt) {
    __syncthreads();  // staging of tile kt complete (vmcnt drained)
    bf16x8 ah[4][2], al[4][2], bh[4][2], bl[4][2];
#pragma unroll
    for (int t = 0; t < 4; ++t) {
#pragma unroll
      for (int kk = 0; kk < 2; ++kk) {
        int ca = ((kk * 4 + q) ^ sw) * 8;
        ah[t][kk] = *(const bf16x8*)(sAh + offA[t] + ca);
        al[t][kk] = *(const bf16x8*)(sAl + offA[t] + ca);
        bh[t][kk] = *(const bf16x8*)(sBh + offB[t] + ca);
        bl[t][kk] = *(const bf16x8*)(sBl + offB[t] + ca);
      }
    }
    __syncthreads();  // all waves done reading LDS
    if (kt < 7) stage((kt + 1) * 64);  // async prefetch overlaps MFMAs
#pragma unroll
    for (int kk = 0; kk < 2; ++kk)
#pragma unroll
      for (int mi = 0; mi < 4; ++mi)
#pragma unroll
        for (int nj = 0; nj < 4; ++nj) {
          f32x4 a = acc[mi][nj];
          a = __builtin_amdgcn_mfma_f32_16x16x32_bf16(al[mi][kk], bh[nj][kk], a, 0, 0, 0);
          a = __builtin_amdgcn_mfma_f32_16x16x32_bf16(ah[mi][kk], bl[nj][kk], a, 0, 0, 0);
          a = __builtin_amdgcn_mfma_f32_16x16x32_bf16(ah[mi][kk], bh[nj][kk], a, 0, 0, 0);
          acc[mi][nj] = a;
        }
  }

  // Epilogue: D col = lane&15, row = (lane>>4)*4 + reg.
#pragma unroll
  for (int mi = 0; mi < 4; ++mi) {
#pragma unroll
    for (int nj = 0; nj < 4; ++nj) {
      int row = bm + (wv >> 1) * 64 + mi * 16 + q * 4;
      int col = bn + (wv & 1) * 64 + nj * 16 + fr;
      float bs = bias[col];
#pragma unroll
      for (int e = 0; e < 4; ++e)
        C[(size_t)(row + e) * 1024 + col] = acc[mi][nj][e] + bs;
    }
  }
}

// ---------------------------------------------------------------------------
// xpd GEMM, resident-weight variant (R11, unchanged): trans-unit softplus
// fused for cols >= 128.
// ---------------------------------------------------------------------------
__global__ __launch_bounds__(256) void xpd_gemm_kernel(
    const u16* __restrict__ A_hi, const u16* __restrict__ A_lo,
    const u16* __restrict__ Bt_hi, const u16* __restrict__ Bt_lo,
    const float* __restrict__ bias, float* __restrict__ C) {
  __shared__ alignas(16) u16 sBh[64 * 512];  // 64 KB
  __shared__ alignas(16) u16 sBl[64 * 512];  // 64 KB

  const int lane = threadIdx.x & 63;
  const int wv = threadIdx.x >> 6;
  const int wr = wv >> 1;
  const int wc = wv & 1;
  const int bm = blockIdx.y * 128;
  const int bn = blockIdx.x * 64;
  const int fr = lane & 15;
  const int q = lane >> 4;

  {
    const int r0 = wv * 16;
#pragma unroll
    for (int i = 0; i < 16; ++i) {
      int r = r0 + i;
      size_t g = (size_t)(bn + r) * 512 + (size_t)(lane ^ (r & 7)) * 8;
      gload_lds16(Bt_hi + g, sBh + r * 512);
      gload_lds16(Bt_lo + g, sBl + r * 512);
    }
  }
  __syncthreads();  // B panel resident for the whole kernel

  size_t arow[4];
#pragma unroll
  for (int mi = 0; mi < 4; ++mi)
    arow[mi] = (size_t)(bm + wr * 64 + mi * 16 + fr) * 512;
  int bcol[2];
#pragma unroll
  for (int nj = 0; nj < 2; ++nj) bcol[nj] = wc * 32 + nj * 16 + fr;

  f32x4 zero = {0.f, 0.f, 0.f, 0.f};
  f32x4 acc[4][2];
#pragma unroll
  for (int i = 0; i < 4; ++i) {
    acc[i][0] = zero;
    acc[i][1] = zero;
  }

#pragma unroll 4
  for (int kt = 0; kt < 16; ++kt) {
    bf16x8 ah[4], al[4], bh[2], bl[2];
    const int kc = kt * 4 + q;
#pragma unroll
    for (int nj = 0; nj < 2; ++nj) {
      int off = bcol[nj] * 512 + ((kc ^ (bcol[nj] & 7)) * 8);
      bh[nj] = *(const bf16x8*)(sBh + off);
      bl[nj] = *(const bf16x8*)(sBl + off);
    }
#pragma unroll
    for (int mi = 0; mi < 4; ++mi) {
      size_t ga = arow[mi] + kt * 32 + q * 8;
      ah[mi] = *(const bf16x8*)(A_hi + ga);
      al[mi] = *(const bf16x8*)(A_lo + ga);
    }
#pragma unroll
    for (int mi = 0; mi < 4; ++mi)
#pragma unroll
      for (int nj = 0; nj < 2; ++nj) {
        f32x4 a = acc[mi][nj];
        a = __builtin_amdgcn_mfma_f32_16x16x32_bf16(al[mi], bh[nj], a, 0, 0, 0);
        a = __builtin_amdgcn_mfma_f32_16x16x32_bf16(ah[mi], bl[nj], a, 0, 0, 0);
        a = __builtin_amdgcn_mfma_f32_16x16x32_bf16(ah[mi], bh[nj], a, 0, 0, 0);
        acc[mi][nj] = a;
      }
  }

  const bool act = (bn >= 128);  // block-uniform: dt columns
#pragma unroll
  for (int mi = 0; mi < 4; ++mi) {
#pragma unroll
    for (int nj = 0; nj < 2; ++nj) {
      int row = bm + wr * 64 + mi * 16 + q * 4;
      int col = bn + wc * 32 + nj * 16 + fr;
      float bs = bias[col];
#pragma unroll
      for (int e = 0; e < 4; ++e) {
        float v = acc[mi][nj][e] + bs;
        if (act) {
          // softplus(v) = ln(1+e^v) = ln2 * log2(1 + 2^(v*log2e))
          float sp = 0.6931471806f * LOG2(1.f + EXP2(v * 1.44269504f));
          v = (v > 20.f) ? v : sp;
        }
        C[(size_t)(row + e) * XPD_LD + col] = v;
      }
    }
  }
}

// ---------------------------------------------------------------------------
// Depthwise causal conv1d (K=4) + bf16 hi/lo split, vectorized x4 over d.
// ---------------------------------------------------------------------------
__global__ __launch_bounds__(256) void conv_split_kernel(
    const float* __restrict__ xz, const float* __restrict__ w,
    const float* __restrict__ cb, float* __restrict__ xc,
    u16* __restrict__ hi, u16* __restrict__ lo) {
  int idx4 = blockIdx.x * 256 + threadIdx.x;  // over NROWS*DM/4
  if (idx4 >= NROWS * DM / 4) return;
  const int d0 = (idx4 & (DM / 4 - 1)) * 4;   // 0,4,...,508
  const int row = idx4 >> 7;                  // b*SEQL + t
  const int t = row & (SEQL - 1);

  float4 acc = *(const float4*)(cb + d0);
#pragma unroll
  for (int k = 0; k < DCONV; ++k) {
    int ts = t + k - (DCONV - 1);
    if (ts >= 0) {
      float4 v = *(const float4*)(xz + (size_t)(row + k - (DCONV - 1)) * (2 * DM) + d0);
      acc.x += w[(d0 + 0) * DCONV + k] * v.x;
      acc.y += w[(d0 + 1) * DCONV + k] * v.y;
      acc.z += w[(d0 + 2) * DCONV + k] * v.z;
      acc.w += w[(d0 + 3) * DCONV + k] * v.w;
    }
  }
  size_t o = (size_t)row * DM + d0;
  *(float4*)(xc + o) = acc;
  ushort4 h, l;
  h.x = f2bf(acc.x); l.x = f2bf(acc.x - bf2f(h.x));
  h.y = f2bf(acc.y); l.y = f2bf(acc.y - bf2f(h.y));
  h.z = f2bf(acc.z); l.z = f2bf(acc.z - bf2f(h.z));
  h.w = f2bf(acc.w); l.w = f2bf(acc.w - bf2f(h.w));
  *(ushort4*)(hi + o) = h;
  *(ushort4*)(lo + o) = l;
}

// ---------------------------------------------------------------------------
// Chunked selective scan (byte-identical to R9's — frozen best).
// xpd layout: Bp = col n, Cp = col 64+n, dt = 128+d.
// ---------------------------------------------------------------------------
__global__ __launch_bounds__(256) void scan_phase1(
    const float* __restrict__ xpd, const float* __restrict__ xc,
    const float* __restrict__ A_log, const float* __restrict__ Bpar,
    float* __restrict__ hout, float* __restrict__ sdt_arr) {
  const int lane = threadIdx.x & 63;
  const int wid = (blockIdx.x << 2) + (threadIdx.x >> 6);  // ch*NC + c
  const int ch = wid >> 5;
  const int c = wid & (NC - 1);
  const int b = ch >> 9;
  const int d = ch & (DM - 1);
  const int n = lane;

  const float aq = -__expf(A_log[d * DST + n]) * 1.44269504f;
  const float bpn = Bpar[d * DST + n];
  float h = 0.f, sdt = 0.f;

  const size_t row0 = (size_t)b * SEQL + (size_t)c * CL;
  const float* dtp = xpd + row0 * XPD_LD + 128 + d;
  const float* up = xc + row0 * DM + d;
  const float* bp = xpd + row0 * XPD_LD + n;

  for (int t0 = 0; t0 < CL; t0 += 4) {
    float dtv[4], uv[4], bpt[4];
#pragma unroll
    for (int j = 0; j < 4; ++j) {
      dtv[j] = dtp[(size_t)(t0 + j) * XPD_LD];
      uv[j] = up[(size_t)(t0 + j) * DM];
      bpt[j] = bp[(size_t)(t0 + j) * XPD_LD];
    }
#pragma unroll
    for (int j = 0; j < 4; ++j) {
      float Ad = EXP2(dtv[j] * aq);
      h = Ad * h + (bpn * bpt[j]) * (dtv[j] * uv[j]);
      sdt += dtv[j];
    }
  }
  hout[(size_t)wid * DST + n] = h;
  if (lane == 0) sdt_arr[wid] = sdt;
}

__global__ __launch_bounds__(256) void scan_phase2(
    const float* __restrict__ A_log, float* __restrict__ hout,
    const float* __restrict__ sdt_arr) {
  const int lane = threadIdx.x & 63;
  const int ch = (blockIdx.x << 2) + (threadIdx.x >> 6);
  const int d = ch & (DM - 1);
  const float aq = -__expf(A_log[d * DST + lane]) * 1.44269504f;

  float tmp[NC], pa[NC];
#pragma unroll
  for (int c = 0; c < NC; ++c) {
    tmp[c] = hout[((size_t)ch * NC + c) * DST + lane];
    pa[c] = EXP2(aq * sdt_arr[ch * NC + c]);
  }
  float h = 0.f;
#pragma unroll
  for (int c = 0; c < NC; ++c) {
    hout[((size_t)ch * NC + c) * DST + lane] = h;
    h = pa[c] * h + tmp[c];
  }
}

__global__ __launch_bounds__(256) void scan_phase3(
    const float* __restrict__ xpd, const float* __restrict__ xc,
    const float* __restrict__ xz,
    const float* __restrict__ A_log, const float* __restrict__ Bpar,
    const float* __restrict__ Cpar, const float* __restrict__ Dpar,
    const float* __restrict__ hin, float* __restrict__ out) {
  __shared__ float W[4][16][68];

  const int lane = threadIdx.x & 63;
  const int wave = threadIdx.x >> 6;
  const int wid = (blockIdx.x << 2) + wave;
  const int ch = wid >> 5;
  const int c = wid & (NC - 1);
  const int b = ch >> 9;
  const int d = ch & (DM - 1);
  const int n = lane;

  const float aq = -__expf(A_log[d * DST + n]) * 1.44269504f;
  const float bpn = Bpar[d * DST + n];
  const float cpn = Cpar[d * DST + n];
  const float Dd = Dpar[d];
  float h = hin[(size_t)wid * DST + n];

  const size_t row0 = (size_t)b * SEQL + (size_t)c * CL;
  const float* dtp = xpd + row0 * XPD_LD + 128 + d;
  const float* up = xc + row0 * DM + d;
  const float* bp = xpd + row0 * XPD_LD + n;
  const float* cp = xpd + row0 * XPD_LD + 64 + n;

  const int tt = lane & 15;
  const int q = lane >> 4;

  for (int t0 = 0; t0 < CL; t0 += 16) {
#pragma unroll
    for (int g = 0; g < 16; g += 4) {
      float dtv[4], uv[4], bpt[4], cpt[4];
#pragma unroll
      for (int j = 0; j < 4; ++j) {
        size_t t = (size_t)(t0 + g + j);
        dtv[j] = dtp[t * XPD_LD];
        uv[j] = up[t * DM];
        bpt[j] = bp[t * XPD_LD];
        cpt[j] = cp[t * XPD_LD];
      }
#pragma unroll
      for (int j = 0; j < 4; ++j) {
        float Ad = EXP2(dtv[j] * aq);
        h = Ad * h + (bpn * bpt[j]) * (dtv[j] * uv[j]);
        W[wave][g + j][n] = (cpn * cpt[j]) * h;
      }
    }
    const float4* wr = (const float4*)&W[wave][tt][q * 16];
    float s = 0.f;
#pragma unroll
    for (int k2 = 0; k2 < 4; ++k2) {
      float4 v = wr[k2];
      s += (v.x + v.y) + (v.z + v.w);
    }
    s += __shfl_xor(s, 16, 64);
    s += __shfl_xor(s, 32, 64);
    if (lane < 16) {
      size_t t = (size_t)(t0 + lane);
      float u = up[t * DM];
      float zz = xz[(row0 + t) * (2 * DM) + DM + d];
      float y = s + Dd * u;
      float sil = zz / (1.f + __expf(-zz));
      out[(row0 + t) * DM + d] = y * sil;
    }
  }
}

// ---------------------------------------------------------------------------
extern "C" void kernel_launch(void* const* d_in, const int* in_sizes, int n_in,
                              void* d_out, int out_size, void* d_ws,
                              size_t ws_size, hipStream_t stream) {
  const float* x = (const float*)d_in[0];           // [B,L,DM]
  const float* in_proj_w = (const float*)d_in[1];   // [DM, 2DM]
  const float* in_proj_b = (const float*)d_in[2];   // [2DM]
  const float* conv_w = (const float*)d_in[3];      // [DM,1,4]
  const float* conv_b = (const float*)d_in[4];      // [DM]
  const float* x_proj_w = (const float*)d_in[5];    // [DM, 160]
  const float* x_proj_b = (const float*)d_in[6];    // [160]
  const float* dt_proj_w = (const float*)d_in[7];   // [32, DM]
  const float* dt_proj_b = (const float*)d_in[8];   // [DM]
  const float* A_log = (const float*)d_in[9];       // [DM, DST]
  const float* B_param = (const float*)d_in[10];    // [DM, DST]
  const float* C_param = (const float*)d_in[11];    // [DM, DST]
  const float* D_param = (const float*)d_in[12];    // [DM]
  float* out = (float*)d_out;

  // Workspace partition (~56 MB total) — R5/R9 layout.
  float* ws = (float*)d_ws;
  float* xz = ws;                            // NROWS*2DM   = 4,194,304 f
  float* xc = xz + (size_t)NROWS * 2 * DM;   // NROWS*DM    = 2,097,152 f
  float* xpd = xc + (size_t)NROWS * DM;      // NROWS*640   = 2,621,440 f
  float* hout = xpd + (size_t)NROWS * XPD_LD;  // 2,097,152 f
  float* sdt = hout + (size_t)BSZ * DM * NC * DST;  // 32,768 f
  float* bias_c = sdt + (size_t)BSZ * DM * NC;      // 640 f
  u16* A_hi = (u16*)(bias_c + 1024);         // 2,097,152 u16
  u16* A_lo = A_hi + (size_t)NROWS * DM;     // 2,097,152 u16
  u16* Wt_in_hi = A_lo + (size_t)NROWS * DM; // 1024*512 u16
  u16* Wt_in_lo = Wt_in_hi + (size_t)1024 * 512;
  u16* Wt_c_hi = Wt_in_lo + (size_t)1024 * 512;  // 640*512 u16
  u16* Wt_c_lo = Wt_c_hi + (size_t)640 * 512;

  // 0) operand prep: splits + combined projection weight/bias
  hipLaunchKernelGGL(split_x_kernel, dim3((NROWS * DM) / (256 * 4)), dim3(256),
                     0, stream, x, A_hi, A_lo);
  hipLaunchKernelGGL(split_w_kernel, dim3(32, 16), dim3(256), 0, stream,
                     in_proj_w, Wt_in_hi, Wt_in_lo);
  hipLaunchKernelGGL(w_combine_kernel, dim3((640 * 512) / 256), dim3(256), 0,
                     stream, x_proj_w, dt_proj_w, Wt_c_hi, Wt_c_lo);
  hipLaunchKernelGGL(bias_combine_kernel, dim3(3), dim3(256), 0, stream,
                     x_proj_b, dt_proj_w, dt_proj_b, bias_c);

  // 1) in_proj via split-bf16 MFMA, BK=64 (half the barrier drains)
  hipLaunchKernelGGL(mfma_split_gemm_bk64, dim3(1024 / 128, NROWS / 128),
                     dim3(256), 0, stream, A_hi, A_lo, Wt_in_hi, Wt_in_lo,
                     in_proj_b, xz);

  // 2) depthwise causal conv + bf16 split of xc (vectorized x4)
  hipLaunchKernelGGL(conv_split_kernel, dim3((NROWS * DM / 4 + 255) / 256),
                     dim3(256), 0, stream, xz, conv_w, conv_b, xc, A_hi, A_lo);

  // 3) fused x_proj+dt_proj via resident GEMM, trans-unit softplus fused
  hipLaunchKernelGGL(xpd_gemm_kernel, dim3(640 / 64, NROWS / 128),
                     dim3(256), 0, stream, A_hi, A_lo, Wt_c_hi, Wt_c_lo,
                     bias_c, xpd);

  // 4) chunked selective scan (R9-frozen)
  {
    dim3 grid((BSZ * DM * NC) / 4);  // 8192 blocks, 4 waves each
    hipLaunchKernelGGL(scan_phase1, grid, dim3(256), 0, stream,
                       xpd, xc, A_log, B_param, hout, sdt);
    hipLaunchKernelGGL(scan_phase2, dim3((BSZ * DM) / 4), dim3(256), 0, stream,
                       A_log, hout, sdt);
    hipLaunchKernelGGL(scan_phase3, grid, dim3(256), 0, stream,
                       xpd, xc, xz, A_log, B_param, C_param, D_param,
                       hout, out);
  }
}